// Round 7
// baseline (1545.958 us; speedup 1.0000x reference)
//
#include <hip/hip_runtime.h>

#define N_NODES 50000
#define N_EDGES 800000
#define HID 128
#define EPS 1e-5f
#define NBKT 782            // ceil(50000/64) buckets of 64 dst nodes
#define ESLICE 6250         // edges per scatter/hist block (128 blocks)

typedef __attribute__((ext_vector_type(8))) short s16x8;   // 8 bf16 (4 VGPRs)
typedef __attribute__((ext_vector_type(4))) float f32x4;   // MFMA acc
typedef __attribute__((ext_vector_type(4))) int i32x4;

__device__ __forceinline__ unsigned short f2bf(float f) {  // RNE f32->bf16
  unsigned int u = __float_as_uint(f);
  u += 0x7fffu + ((u >> 16) & 1u);
  return (unsigned short)(u >> 16);
}
__device__ __forceinline__ unsigned int pack2(float a, float b) {
  return (unsigned int)f2bf(a) | ((unsigned int)f2bf(b) << 16);
}
__device__ __forceinline__ float bflo(unsigned int u) { return __uint_as_float(u << 16); }
__device__ __forceinline__ float bfhi(unsigned int u) { return __uint_as_float(u & 0xffff0000u); }
__device__ __forceinline__ float bf2f(unsigned short u) { return __uint_as_float((unsigned int)u << 16); }

// ================= weight prep (blocks 0..448)  ||  bucket hist (blocks 449..576) =================
__global__ __launch_bounds__(256) void prep_hist_kernel(
    const float* __restrict__ W_enc, const float* __restrict__ W_out,
    const float* __restrict__ Wm1, const float* __restrict__ Wu,
    const float* __restrict__ Wm2, const float* __restrict__ bm2,
    unsigned int* __restrict__ Wenc_b, unsigned int* __restrict__ Wout_b,
    unsigned int* __restrict__ Wpq_b, unsigned short* __restrict__ Wcat_b,
    float* __restrict__ bfold, const int* __restrict__ ei, int* __restrict__ bcounts) {
  __shared__ int lhist[NBKT];
  const int b = blockIdx.x, t = threadIdx.x;
  if (b >= 449) {  // ---- bucket histogram ----
    const int e0 = (b - 449) * ESLICE;
    for (int i = t; i < NBKT; i += 256) lhist[i] = 0;
    __syncthreads();
    for (int e = e0 + t; e < e0 + ESLICE; e += 256)
      atomicAdd(&lhist[ei[N_EDGES + e] >> 6], 1);
    __syncthreads();
    for (int i = t; i < NBKT; i += 256)
      if (lhist[i]) atomicAdd(&bcounts[i], lhist[i]);
    return;
  }
  if (b < 32) {            // W_enc: 8192 uints
    int i = b * 256 + t;
    Wenc_b[i] = pack2(W_enc[2 * i], W_enc[2 * i + 1]);
  } else if (b < 64) {     // W_out
    int i = (b - 32) * 256 + t;
    Wout_b[i] = pack2(W_out[2 * i], W_out[2 * i + 1]);
  } else if (b < 192) {    // repack Wm1 -> Wpq [l][256 rows][128 k]
    int i = (b - 64) * 256 + t;  // 32768
    int k2 = i & 63;
    int c = (i >> 6) & 255;
    int l = i >> 14;
    const float* srow = Wm1 + ((size_t)l * 128 + (c & 127)) * 256 + ((c >> 7) << 7);
    Wpq_b[i] = pack2(srow[2 * k2], srow[2 * k2 + 1]);
  } else if (b < 448) {    // Wcat: [l][128 rows][256 k], hi-k = Wu_b @ Wm2 fold
    int i = (b - 192) * 256 + t;  // 65536
    int k = i & 255, c = (i >> 8) & 127, l = i >> 15;
    const float* wrow = Wu + ((size_t)l * 128 + c) * 256;
    float v;
    if (k < 128) {
      v = wrow[k];
    } else {
      const float* wb = wrow + 128;
      const float* m2 = Wm2 + (size_t)l * 128 * 128 + (k - 128);
      float s = 0.f;
      for (int j = 0; j < 128; ++j) s += wb[j] * m2[(size_t)j * 128];
      v = s;
    }
    Wcat_b[i] = f2bf(v);
  } else {                 // bfold[l][c] = Wu_b[l][c][:] . bm2[l]
    int l = t >> 7, c = t & 127;
    const float* wb = Wu + ((size_t)l * 128 + c) * 256 + 128;
    const float* bv = bm2 + l * 128;
    float s = 0.f;
    for (int j = 0; j < 128; ++j) s += wb[j] * bv[j];
    bfold[t] = s;
  }
}

// ================= bucket scan: one block, one pass (NBKT=782 < 1024) =================
__global__ __launch_bounds__(1024) void bscan_kernel(const int* __restrict__ bcounts,
                                                     int* __restrict__ boff,
                                                     int* __restrict__ bcursor) {
  __shared__ int wtot[16];
  const int t = threadIdx.x, lane = t & 63, w = t >> 6;
  int v = (t < NBKT) ? bcounts[t] : 0;
  int s = v;
#pragma unroll
  for (int off = 1; off < 64; off <<= 1) {
    int tt = __shfl_up(s, off);
    if (lane >= off) s += tt;
  }
  if (lane == 63) wtot[w] = s;
  __syncthreads();
  int woff = 0;
#pragma unroll
  for (int j = 0; j < 16; ++j) { int tv = wtot[j]; if (j < w) woff += tv; }
  int excl = woff + (s - v);
  if (t < NBKT) { boff[t] = excl; bcursor[t] = excl; }
  if (t == NBKT) boff[NBKT] = excl;  // v=0 here -> excl == total
}

// ================= bucket scatter: 2-pass LDS counting sort per 6250-edge slice =================
// writes ebuf packed: src (bits 0..15) | dst_local (bits 16..21), grouped by bucket,
// flushed as contiguous bursts (one cursor atomic per bucket per block).
__global__ __launch_bounds__(256) void bscatter_kernel(const int* __restrict__ ei,
                                                       int* __restrict__ bcursor,
                                                       unsigned int* __restrict__ ebuf) {
  __shared__ int lhist[784];
  __shared__ int lstart[784];
  __shared__ int lcur[784];
  __shared__ int gbase[784];
  __shared__ unsigned int staged[ESLICE];
  __shared__ int wtot[4];
  const int t = threadIdx.x, lane = t & 63, w = t >> 6;
  const int e0 = blockIdx.x * ESLICE;

  for (int i = t; i < 784; i += 256) lhist[i] = 0;
  __syncthreads();
  for (int e = e0 + t; e < e0 + ESLICE; e += 256)
    atomicAdd(&lhist[ei[N_EDGES + e] >> 6], 1);
  __syncthreads();

  // local exclusive scan over buckets: thread t owns 4t..4t+3 (t<196)
  int tsum = 0;
  if (t < 196) tsum = lhist[4 * t] + lhist[4 * t + 1] + lhist[4 * t + 2] + lhist[4 * t + 3];
  int inc = tsum;
#pragma unroll
  for (int off = 1; off < 64; off <<= 1) {
    int tt = __shfl_up(inc, off);
    if (lane >= off) inc += tt;
  }
  if (lane == 63) wtot[w] = inc;
  __syncthreads();
  int woff = 0;
#pragma unroll
  for (int j = 0; j < 4; ++j) { int tv = wtot[j]; if (j < w) woff += tv; }
  if (t < 196) {
    int run = woff + inc - tsum;
#pragma unroll
    for (int j = 0; j < 4; ++j) {
      lstart[4 * t + j] = run;
      lcur[4 * t + j] = run;
      run += lhist[4 * t + j];
    }
  }
  // reserve global ranges (independent atomics, pipelined)
  for (int bk = t; bk < NBKT; bk += 256)
    gbase[bk] = lhist[bk] ? atomicAdd(&bcursor[bk], lhist[bk]) : 0;
  __syncthreads();

  // pass 2: place into staged, grouped by bucket
  for (int e = e0 + t; e < e0 + ESLICE; e += 256) {
    int s = ei[e], d = ei[N_EDGES + e];
    int pos = atomicAdd(&lcur[d >> 6], 1);
    staged[pos] = (unsigned int)s | ((unsigned int)(d & 63) << 16);
  }
  __syncthreads();

  // flush: contiguous burst per bucket
  for (int bk = w; bk < NBKT; bk += 4) {
    int cnt = lhist[bk];
    if (!cnt) continue;
    int gb = gbase[bk], ls = lstart[bk];
    for (int i = lane; i < cnt; i += 64) ebuf[gb + i] = staged[ls + i];
  }
}

// ================= aggregation v2: LDS f32 accumulators per 64-node bucket =================
// r[n] = sum_{e: dst=n} relu(p[src] + q[n] + bm1);  also counts[n] = deg(n).
__global__ __launch_bounds__(256) void aggregate2_kernel(
    const unsigned int* __restrict__ pq32, const float* __restrict__ bm1,
    const int* __restrict__ boff, const unsigned int* __restrict__ ebuf,
    unsigned int* __restrict__ rb32, int* __restrict__ counts) {
  __shared__ float acc[64 * 128];     // 32 KB
  __shared__ unsigned int qb[64 * 64];  // q+bm1, bf16 pairs, 16 KB
  __shared__ int degl[64];
  const int t = threadIdx.x;
  const int node0 = blockIdx.x * 64;
  const int nvalid = min(64, N_NODES - node0);

  for (int i = t; i < 64 * 128; i += 256) acc[i] = 0.f;
  for (int i = t; i < nvalid * 64; i += 256) {
    int row = i >> 6, u = i & 63;
    unsigned int qv = pq32[(size_t)(node0 + row) * 128 + 64 + u];
    qb[i] = pack2(bflo(qv) + bm1[2 * u], bfhi(qv) + bm1[2 * u + 1]);
  }
  if (t < 64) degl[t] = 0;
  __syncthreads();

  const int l = t & 31;  // half-wave lane; handles channel pairs l and l+32
  const int i1 = boff[blockIdx.x + 1];
  for (int e = boff[blockIdx.x] + (t >> 5); e < i1; e += 8) {
    unsigned int pk = ebuf[e];
    int src = pk & 0xffff;
    int dl = (pk >> 16) & 63;
    unsigned int u0 = pq32[(size_t)src * 128 + l];        // p ch 2l,2l+1
    unsigned int u1 = pq32[(size_t)src * 128 + 32 + l];   // p ch 64+2l,64+2l+1
    unsigned int q0 = qb[dl * 64 + l];
    unsigned int q1 = qb[dl * 64 + 32 + l];
    float* arow = acc + dl * 128;
    atomicAdd(&arow[2 * l],          fmaxf(bflo(u0) + bflo(q0), 0.f));
    atomicAdd(&arow[2 * l + 1],      fmaxf(bfhi(u0) + bfhi(q0), 0.f));
    atomicAdd(&arow[64 + 2 * l],     fmaxf(bflo(u1) + bflo(q1), 0.f));
    atomicAdd(&arow[64 + 2 * l + 1], fmaxf(bfhi(u1) + bfhi(q1), 0.f));
    if (l == 0) atomicAdd(&degl[dl], 1);
  }
  __syncthreads();

  for (int i = t; i < nvalid * 64; i += 256) {
    int row = i >> 6, u = i & 63;
    rb32[(size_t)(node0 + row) * 64 + u] = pack2(acc[row * 128 + 2 * u], acc[row * 128 + 2 * u + 1]);
  }
  if (t < nvalid) counts[node0 + t] = degl[t];
}

// ================= persistent-B MFMA GEMM (unchanged from R6) =================
template <int KS, bool AF32, bool DUAL, int MODE>
__global__ __launch_bounds__(256, DUAL ? 1 : 2) void gemm3(
    const void* __restrict__ A0v, const unsigned short* __restrict__ A1,
    const unsigned short* __restrict__ W, const float* __restrict__ bias,
    const int* __restrict__ deg, const float* __restrict__ bias2,
    const float* __restrict__ gamma, const float* __restrict__ beta,
    const unsigned short* __restrict__ hres, float* __restrict__ outF,
    unsigned short* __restrict__ outB, int outw) {
  constexpr int KW = KS * 32;
  constexpr int NFRAG = KS * 8;
  __shared__ short Bs[NFRAG * 512];
  const int lane = threadIdx.x & 63;
  const int w = threadIdx.x >> 6;
  const int cl = lane & 15;
  const int kb = (lane >> 4) * 8;
  const int co = blockIdx.y * 128;
  W += (size_t)blockIdx.y * 128 * KW;

  for (int f = w; f < NFRAG; f += 4) {
    int nt = f & 7, ks = f >> 3;
    s16x8 bv = *(const s16x8*)(W + (size_t)(nt * 16 + cl) * KW + ks * 32 + kb);
    *(s16x8*)(Bs + f * 512 + lane * 8) = bv;
  }
  __syncthreads();

  s16x8 breg[KS][8];
#pragma unroll
  for (int ks = 0; ks < KS; ++ks)
#pragma unroll
    for (int nt = 0; nt < 8; ++nt)
      breg[ks][nt] = *(const s16x8*)(Bs + (ks * 8 + nt) * 512 + lane * 8);

  float bs[8], b2[8], gs[8], bes[8];
#pragma unroll
  for (int nt = 0; nt < 8; ++nt) {
    int col = nt * 16 + cl;
    bs[nt] = bias ? bias[col] : 0.f;
    if constexpr (MODE == 2) {
      b2[nt] = bias2[col];
      gs[nt] = gamma[col];
      bes[nt] = beta[col];
    }
  }

  const int step = gridDim.x * 4;
  for (int rt = blockIdx.x * 4 + w; rt < 3125; rt += step) {  // 3125*16 == 50000
    const int arow = rt * 16 + cl;
    f32x4 acc[8];
#pragma unroll
    for (int i = 0; i < 8; ++i) acc[i] = (f32x4){0.f, 0.f, 0.f, 0.f};
#pragma unroll
    for (int ks = 0; ks < KS; ++ks) {
      s16x8 a;
      if constexpr (AF32) {
        const float* ap = (const float*)A0v + (size_t)arow * HID + ks * 32 + kb;
        float4 lo = *(const float4*)ap;
        float4 hi = *(const float4*)(ap + 4);
        i32x4 ai = {(int)pack2(lo.x, lo.y), (int)pack2(lo.z, lo.w),
                    (int)pack2(hi.x, hi.y), (int)pack2(hi.z, hi.w)};
        a = __builtin_bit_cast(s16x8, ai);
      } else if constexpr (DUAL) {
        const unsigned short* base = (ks < KS / 2) ? (const unsigned short*)A0v : A1;
        int kss = (ks < KS / 2) ? ks : ks - KS / 2;
        a = *(const s16x8*)(base + (size_t)arow * HID + kss * 32 + kb);
      } else {
        a = *(const s16x8*)((const unsigned short*)A0v + (size_t)arow * HID + ks * 32 + kb);
      }
#pragma unroll
      for (int nt = 0; nt < 8; ++nt)
        acc[nt] = __builtin_amdgcn_mfma_f32_16x16x32_bf16(a, breg[ks][nt], acc[nt], 0, 0, 0);
    }

    const int rbase = rt * 16 + (lane >> 4) * 4;
    if constexpr (MODE == 2) {
#pragma unroll
      for (int reg = 0; reg < 4; ++reg) {
        int row = rbase + reg;
        float dv = (float)deg[row];
        float v[8];
        float s = 0.f, s2 = 0.f;
#pragma unroll
        for (int nt = 0; nt < 8; ++nt) {
          float hv = bf2f(hres[(size_t)row * HID + nt * 16 + cl]);
          v[nt] = acc[nt][reg] + bs[nt] + dv * b2[nt] + hv;
          s += v[nt];
          s2 += v[nt] * v[nt];
        }
#pragma unroll
        for (int m = 1; m < 16; m <<= 1) {
          s += __shfl_xor(s, m);
          s2 += __shfl_xor(s2, m);
        }
        float mu = s * (1.f / 128.f);
        float var = s2 * (1.f / 128.f) - mu * mu;
        float inv = rsqrtf(var + EPS);
#pragma unroll
        for (int nt = 0; nt < 8; ++nt) {
          float o = (v[nt] - mu) * inv * gs[nt] + bes[nt];
          outB[(size_t)row * HID + nt * 16 + cl] = f2bf(o);
        }
      }
    } else {
#pragma unroll
      for (int reg = 0; reg < 4; ++reg) {
        int row = rbase + reg;
#pragma unroll
        for (int nt = 0; nt < 8; ++nt) {
          float vv = acc[nt][reg] + bs[nt];
          if constexpr (MODE == 0) outF[(size_t)row * outw + co + nt * 16 + cl] = vv;
          else outB[(size_t)row * outw + co + nt * 16 + cl] = f2bf(vv);
        }
      }
    }
  }
}

extern "C" void kernel_launch(void* const* d_in, const int* in_sizes, int n_in,
                              void* d_out, int out_size, void* d_ws, size_t ws_size,
                              hipStream_t stream) {
  const float* x     = (const float*)d_in[0];
  const int*   ei    = (const int*)d_in[1];
  const float* W_enc = (const float*)d_in[2];
  const float* b_enc = (const float*)d_in[3];
  const float* Wm1   = (const float*)d_in[4];
  const float* bm1   = (const float*)d_in[5];
  const float* Wm2   = (const float*)d_in[6];
  const float* bm2   = (const float*)d_in[7];
  const float* Wu    = (const float*)d_in[8];
  const float* bu    = (const float*)d_in[9];
  const float* gamma = (const float*)d_in[10];
  const float* beta  = (const float*)d_in[11];
  const float* W_out = (const float*)d_in[12];
  const float* b_out = (const float*)d_in[13];
  float* out = (float*)d_out;

  char* ws = (char*)d_ws;
  const size_t NBH = (size_t)N_NODES * HID * 2;  // 12.8 MB

  unsigned short* hb = (unsigned short*)(ws);            // [N][128] bf16
  unsigned short* pq = (unsigned short*)(ws + NBH);      // [N][256] bf16
  unsigned short* rb = (unsigned short*)(ws + 3 * NBH);  // [N][128] bf16
  char* wp = ws + 4 * NBH;
  unsigned short* Wenc_b = (unsigned short*)wp;          // 16384
  unsigned short* Wout_b = Wenc_b + 16384;               // 16384
  unsigned short* Wpq_b  = Wout_b + 16384;               // 2*32768
  unsigned short* Wcat_b = Wpq_b + 65536;                // 2*32768
  float*          bfold  = (float*)(Wcat_b + 65536);     // 256
  int* counts  = (int*)(bfold + 256);                    // [N] deg
  int* boff    = counts + N_NODES;                       // NBKT+1
  int* bcounts = boff + NBKT + 1;                        // NBKT
  int* bcursor = bcounts + NBKT;                         // NBKT
  unsigned int* ebuf = (unsigned int*)(bcursor + NBKT);  // [E] packed src|dst_local

  // zero bucket counts, then prep weights || bucket hist
  hipMemsetAsync(bcounts, 0, NBKT * sizeof(int), stream);
  prep_hist_kernel<<<449 + 128, 256, 0, stream>>>(
      W_enc, W_out, Wm1, Wu, Wm2, bm2, (unsigned int*)Wenc_b, (unsigned int*)Wout_b,
      (unsigned int*)Wpq_b, Wcat_b, bfold, ei, bcounts);
  bscan_kernel<<<1, 1024, 0, stream>>>(bcounts, boff, bcursor);
  bscatter_kernel<<<128, 256, 0, stream>>>(ei, bcursor, ebuf);

  // h = x @ W_enc.T + b_enc  -> bf16 hb
  gemm3<4, true, false, 1><<<512, 256, 0, stream>>>(
      x, nullptr, Wenc_b, b_enc, nullptr, nullptr, nullptr, nullptr, nullptr,
      nullptr, hb, HID);

  for (int l = 0; l < 2; ++l) {
    const unsigned short* Wpql  = Wpq_b + l * 32768;
    const unsigned short* Wcatl = Wcat_b + l * 32768;
    const float* bm1l = bm1 + l * HID;
    const float* bul  = bu + l * HID;
    const float* bfl  = bfold + l * HID;
    const float* gl   = gamma + l * HID;
    const float* bl   = beta + l * HID;

    // pq = h @ [Wm1a|Wm1b].T -> [N][256] bf16 (blockIdx.y halves)
    gemm3<4, false, false, 1><<<dim3(512, 2), 256, 0, stream>>>(
        hb, nullptr, Wpql, nullptr, nullptr, nullptr, nullptr, nullptr, nullptr,
        nullptr, pq, 256);
    // r = segsum(relu(p[src]+q[dst]+bm1)), deg -> counts
    aggregate2_kernel<<<NBKT, 256, 0, stream>>>((const unsigned int*)pq, bm1l, boff,
                                                ebuf, (unsigned int*)rb, counts);
    // h = LN(h + h@Wua.T + r@Wfold.T + deg*bfold + bu)*gamma+beta (in-place)
    gemm3<8, false, true, 2><<<256, 256, 0, stream>>>(
        hb, rb, Wcatl, bul, counts, bfl, gl, bl, hb, nullptr, hb, HID);
  }

  // out = h @ W_out.T + b_out (f32)
  gemm3<4, false, false, 0><<<512, 256, 0, stream>>>(
      hb, nullptr, Wout_b, b_out, nullptr, nullptr, nullptr, nullptr, nullptr,
      out, nullptr, HID);
}

// Round 8
// 253.287 us; speedup vs baseline: 6.1036x; 6.1036x over previous
//
#include <hip/hip_runtime.h>

#define N_NODES 50000
#define N_EDGES 800000
#define HID 128
#define EPS 1e-5f
#define NBKT 782            // ceil(50000/64) buckets of 64 dst nodes
#define ESLICE 6250         // edges per scatter/hist block (128 blocks)

typedef __attribute__((ext_vector_type(8))) short s16x8;   // 8 bf16 (4 VGPRs)
typedef __attribute__((ext_vector_type(4))) float f32x4;   // MFMA acc
typedef __attribute__((ext_vector_type(4))) int i32x4;

__device__ __forceinline__ unsigned short f2bf(float f) {  // RNE f32->bf16
  unsigned int u = __float_as_uint(f);
  u += 0x7fffu + ((u >> 16) & 1u);
  return (unsigned short)(u >> 16);
}
__device__ __forceinline__ unsigned int pack2(float a, float b) {
  return (unsigned int)f2bf(a) | ((unsigned int)f2bf(b) << 16);
}
__device__ __forceinline__ float bflo(unsigned int u) { return __uint_as_float(u << 16); }
__device__ __forceinline__ float bfhi(unsigned int u) { return __uint_as_float(u & 0xffff0000u); }
__device__ __forceinline__ float bf2f(unsigned short u) { return __uint_as_float((unsigned int)u << 16); }

// ================= weight prep (blocks 0..448)  ||  bucket hist (blocks 449..576) =================
__global__ __launch_bounds__(256) void prep_hist_kernel(
    const float* __restrict__ W_enc, const float* __restrict__ W_out,
    const float* __restrict__ Wm1, const float* __restrict__ Wu,
    const float* __restrict__ Wm2, const float* __restrict__ bm2,
    unsigned int* __restrict__ Wenc_b, unsigned int* __restrict__ Wout_b,
    unsigned int* __restrict__ Wpq_b, unsigned short* __restrict__ Wcat_b,
    float* __restrict__ bfold, const int* __restrict__ ei, int* __restrict__ bcounts) {
  __shared__ int lhist[NBKT];
  const int b = blockIdx.x, t = threadIdx.x;
  if (b >= 449) {  // ---- bucket histogram ----
    const int e0 = (b - 449) * ESLICE;
    for (int i = t; i < NBKT; i += 256) lhist[i] = 0;
    __syncthreads();
    for (int e = e0 + t; e < e0 + ESLICE; e += 256)
      atomicAdd(&lhist[ei[N_EDGES + e] >> 6], 1);
    __syncthreads();
    for (int i = t; i < NBKT; i += 256)
      if (lhist[i]) atomicAdd(&bcounts[i], lhist[i]);
    return;
  }
  if (b < 32) {            // W_enc: 8192 uints
    int i = b * 256 + t;
    Wenc_b[i] = pack2(W_enc[2 * i], W_enc[2 * i + 1]);
  } else if (b < 64) {     // W_out
    int i = (b - 32) * 256 + t;
    Wout_b[i] = pack2(W_out[2 * i], W_out[2 * i + 1]);
  } else if (b < 192) {    // repack Wm1 -> Wpq [l][256 rows][128 k]
    int i = (b - 64) * 256 + t;  // 32768
    int k2 = i & 63;
    int c = (i >> 6) & 255;
    int l = i >> 14;
    const float* srow = Wm1 + ((size_t)l * 128 + (c & 127)) * 256 + ((c >> 7) << 7);
    Wpq_b[i] = pack2(srow[2 * k2], srow[2 * k2 + 1]);
  } else if (b < 448) {    // Wcat: [l][128 rows][256 k], hi-k = Wu_b @ Wm2 fold
    int i = (b - 192) * 256 + t;  // 65536
    int k = i & 255, c = (i >> 8) & 127, l = i >> 15;
    const float* wrow = Wu + ((size_t)l * 128 + c) * 256;
    float v;
    if (k < 128) {
      v = wrow[k];
    } else {
      const float* wb = wrow + 128;
      const float* m2 = Wm2 + (size_t)l * 128 * 128 + (k - 128);
      float s = 0.f;
      for (int j = 0; j < 128; ++j) s += wb[j] * m2[(size_t)j * 128];
      v = s;
    }
    Wcat_b[i] = f2bf(v);
  } else {                 // bfold[l][c] = Wu_b[l][c][:] . bm2[l]
    int l = t >> 7, c = t & 127;
    const float* wb = Wu + ((size_t)l * 128 + c) * 256 + 128;
    const float* bv = bm2 + l * 128;
    float s = 0.f;
    for (int j = 0; j < 128; ++j) s += wb[j] * bv[j];
    bfold[t] = s;
  }
}

// ================= bucket scan: one block, one pass (NBKT=782 < 1024) =================
__global__ __launch_bounds__(1024) void bscan_kernel(const int* __restrict__ bcounts,
                                                     int* __restrict__ boff,
                                                     int* __restrict__ bcursor) {
  __shared__ int wtot[16];
  const int t = threadIdx.x, lane = t & 63, w = t >> 6;
  int v = (t < NBKT) ? bcounts[t] : 0;
  int s = v;
#pragma unroll
  for (int off = 1; off < 64; off <<= 1) {
    int tt = __shfl_up(s, off);
    if (lane >= off) s += tt;
  }
  if (lane == 63) wtot[w] = s;
  __syncthreads();
  int woff = 0;
#pragma unroll
  for (int j = 0; j < 16; ++j) { int tv = wtot[j]; if (j < w) woff += tv; }
  int excl = woff + (s - v);
  if (t < NBKT) { boff[t] = excl; bcursor[t] = excl; }
  if (t == NBKT) boff[NBKT] = excl;  // v=0 here -> excl == total
}

// ================= bucket scatter: 2-pass LDS counting sort per 6250-edge slice =================
// writes ebuf packed: src (bits 0..15) | dst_local (bits 16..21), grouped by bucket,
// flushed as contiguous bursts (one cursor atomic per bucket per block).
__global__ __launch_bounds__(256) void bscatter_kernel(const int* __restrict__ ei,
                                                       int* __restrict__ bcursor,
                                                       unsigned int* __restrict__ ebuf) {
  __shared__ int lhist[784];
  __shared__ int lstart[784];
  __shared__ int lcur[784];
  __shared__ int gbase[784];
  __shared__ unsigned int staged[ESLICE];
  __shared__ int wtot[4];
  const int t = threadIdx.x, lane = t & 63, w = t >> 6;
  const int e0 = blockIdx.x * ESLICE;

  for (int i = t; i < 784; i += 256) lhist[i] = 0;
  __syncthreads();
  for (int e = e0 + t; e < e0 + ESLICE; e += 256)
    atomicAdd(&lhist[ei[N_EDGES + e] >> 6], 1);
  __syncthreads();

  // local exclusive scan over buckets: thread t owns 4t..4t+3 (t<196)
  int tsum = 0;
  if (t < 196) tsum = lhist[4 * t] + lhist[4 * t + 1] + lhist[4 * t + 2] + lhist[4 * t + 3];
  int inc = tsum;
#pragma unroll
  for (int off = 1; off < 64; off <<= 1) {
    int tt = __shfl_up(inc, off);
    if (lane >= off) inc += tt;
  }
  if (lane == 63) wtot[w] = inc;
  __syncthreads();
  int woff = 0;
#pragma unroll
  for (int j = 0; j < 4; ++j) { int tv = wtot[j]; if (j < w) woff += tv; }
  if (t < 196) {
    int run = woff + inc - tsum;
#pragma unroll
    for (int j = 0; j < 4; ++j) {
      lstart[4 * t + j] = run;
      lcur[4 * t + j] = run;
      run += lhist[4 * t + j];
    }
  }
  // reserve global ranges (independent atomics, pipelined)
  for (int bk = t; bk < NBKT; bk += 256)
    gbase[bk] = lhist[bk] ? atomicAdd(&bcursor[bk], lhist[bk]) : 0;
  __syncthreads();

  // pass 2: place into staged, grouped by bucket
  for (int e = e0 + t; e < e0 + ESLICE; e += 256) {
    int s = ei[e], d = ei[N_EDGES + e];
    int pos = atomicAdd(&lcur[d >> 6], 1);
    staged[pos] = (unsigned int)s | ((unsigned int)(d & 63) << 16);
  }
  __syncthreads();

  // flush: contiguous burst per bucket
  for (int bk = w; bk < NBKT; bk += 4) {
    int cnt = lhist[bk];
    if (!cnt) continue;
    int gb = gbase[bk], ls = lstart[bk];
    for (int i = lane; i < cnt; i += 64) ebuf[gb + i] = staged[ls + i];
  }
}

// ================= sort64: bucket -> exact per-node CSR (no FP atomics anywhere) =================
// block = one bucket; 64-bin int histogram + single-wave scan; writes exact node offsets
// noff (global CSR: contiguous across buckets), deg counts, and esrc grouped by exact dst.
__global__ __launch_bounds__(256) void sort64_kernel(const unsigned int* __restrict__ ebuf,
                                                     const int* __restrict__ boff,
                                                     unsigned int* __restrict__ esrc,
                                                     int* __restrict__ noff,
                                                     int* __restrict__ counts) {
  __shared__ int hist[64];
  __shared__ int lcur[64];
  const int b = blockIdx.x, t = threadIdx.x;
  const int e0 = boff[b], e1 = boff[b + 1];
  if (t < 64) hist[t] = 0;
  __syncthreads();
  for (int e = e0 + t; e < e1; e += 256)
    atomicAdd(&hist[(ebuf[e] >> 16) & 63], 1);
  __syncthreads();
  if (t < 64) {  // wave 0: exclusive scan of 64 bins
    int v = hist[t];
    int s = v;
#pragma unroll
    for (int off = 1; off < 64; off <<= 1) {
      int tt = __shfl_up(s, off);
      if (t >= off) s += tt;
    }
    lcur[t] = s - v;
    int node = b * 64 + t;
    if (node < N_NODES) {
      noff[node] = e0 + s - v;
      counts[node] = v;
    }
  }
  __syncthreads();
  for (int e = e0 + t; e < e1; e += 256) {
    unsigned int pk = ebuf[e];
    int pos = atomicAdd(&lcur[(pk >> 16) & 63], 1);
    esrc[e0 + pos] = pk & 0xffffu;
  }
  if (b == NBKT - 1 && t == 0) noff[N_NODES] = e1;
}

// ================= edge aggregation: exact runs, 32 lanes/node, uint2 loads, unroll 4 =================
__global__ __launch_bounds__(256) void aggregate3_kernel(
    const unsigned int* __restrict__ pq32, const float* __restrict__ bm1,
    const int* __restrict__ noff, const unsigned int* __restrict__ esrc,
    unsigned int* __restrict__ rb32) {
  const int node = blockIdx.x * 8 + (threadIdx.x >> 5);
  const int l = threadIdx.x & 31;
  uint2 qv = *(const uint2*)(pq32 + (size_t)node * 128 + 64 + 2 * l);
  float4 bv = *(const float4*)(bm1 + 4 * l);
  float q0 = bflo(qv.x) + bv.x, q1 = bfhi(qv.x) + bv.y;
  float q2 = bflo(qv.y) + bv.z, q3 = bfhi(qv.y) + bv.w;
  float a0 = 0.f, a1 = 0.f, a2 = 0.f, a3 = 0.f;
  const int i1 = noff[node + 1];
  int idx = noff[node];
  for (; idx + 3 < i1; idx += 4) {
    int s0 = esrc[idx], s1 = esrc[idx + 1], s2 = esrc[idx + 2], s3 = esrc[idx + 3];
    uint2 u0 = *(const uint2*)(pq32 + (size_t)s0 * 128 + 2 * l);
    uint2 u1 = *(const uint2*)(pq32 + (size_t)s1 * 128 + 2 * l);
    uint2 u2 = *(const uint2*)(pq32 + (size_t)s2 * 128 + 2 * l);
    uint2 u3 = *(const uint2*)(pq32 + (size_t)s3 * 128 + 2 * l);
    a0 += fmaxf(bflo(u0.x) + q0, 0.f) + fmaxf(bflo(u1.x) + q0, 0.f) +
          fmaxf(bflo(u2.x) + q0, 0.f) + fmaxf(bflo(u3.x) + q0, 0.f);
    a1 += fmaxf(bfhi(u0.x) + q1, 0.f) + fmaxf(bfhi(u1.x) + q1, 0.f) +
          fmaxf(bfhi(u2.x) + q1, 0.f) + fmaxf(bfhi(u3.x) + q1, 0.f);
    a2 += fmaxf(bflo(u0.y) + q2, 0.f) + fmaxf(bflo(u1.y) + q2, 0.f) +
          fmaxf(bflo(u2.y) + q2, 0.f) + fmaxf(bflo(u3.y) + q2, 0.f);
    a3 += fmaxf(bfhi(u0.y) + q3, 0.f) + fmaxf(bfhi(u1.y) + q3, 0.f) +
          fmaxf(bfhi(u2.y) + q3, 0.f) + fmaxf(bfhi(u3.y) + q3, 0.f);
  }
  for (; idx < i1; ++idx) {
    uint2 u0 = *(const uint2*)(pq32 + (size_t)esrc[idx] * 128 + 2 * l);
    a0 += fmaxf(bflo(u0.x) + q0, 0.f);
    a1 += fmaxf(bfhi(u0.x) + q1, 0.f);
    a2 += fmaxf(bflo(u0.y) + q2, 0.f);
    a3 += fmaxf(bfhi(u0.y) + q3, 0.f);
  }
  uint2 r;
  r.x = pack2(a0, a1);
  r.y = pack2(a2, a3);
  *(uint2*)(rb32 + (size_t)node * 64 + 2 * l) = r;
}

// ================= persistent-B MFMA GEMM (unchanged) =================
template <int KS, bool AF32, bool DUAL, int MODE>
__global__ __launch_bounds__(256, DUAL ? 1 : 2) void gemm3(
    const void* __restrict__ A0v, const unsigned short* __restrict__ A1,
    const unsigned short* __restrict__ W, const float* __restrict__ bias,
    const int* __restrict__ deg, const float* __restrict__ bias2,
    const float* __restrict__ gamma, const float* __restrict__ beta,
    const unsigned short* __restrict__ hres, float* __restrict__ outF,
    unsigned short* __restrict__ outB, int outw) {
  constexpr int KW = KS * 32;
  constexpr int NFRAG = KS * 8;
  __shared__ short Bs[NFRAG * 512];
  const int lane = threadIdx.x & 63;
  const int w = threadIdx.x >> 6;
  const int cl = lane & 15;
  const int kb = (lane >> 4) * 8;
  const int co = blockIdx.y * 128;
  W += (size_t)blockIdx.y * 128 * KW;

  for (int f = w; f < NFRAG; f += 4) {
    int nt = f & 7, ks = f >> 3;
    s16x8 bv = *(const s16x8*)(W + (size_t)(nt * 16 + cl) * KW + ks * 32 + kb);
    *(s16x8*)(Bs + f * 512 + lane * 8) = bv;
  }
  __syncthreads();

  s16x8 breg[KS][8];
#pragma unroll
  for (int ks = 0; ks < KS; ++ks)
#pragma unroll
    for (int nt = 0; nt < 8; ++nt)
      breg[ks][nt] = *(const s16x8*)(Bs + (ks * 8 + nt) * 512 + lane * 8);

  float bs[8], b2[8], gs[8], bes[8];
#pragma unroll
  for (int nt = 0; nt < 8; ++nt) {
    int col = nt * 16 + cl;
    bs[nt] = bias ? bias[col] : 0.f;
    if constexpr (MODE == 2) {
      b2[nt] = bias2[col];
      gs[nt] = gamma[col];
      bes[nt] = beta[col];
    }
  }

  const int step = gridDim.x * 4;
  for (int rt = blockIdx.x * 4 + w; rt < 3125; rt += step) {  // 3125*16 == 50000
    const int arow = rt * 16 + cl;
    f32x4 acc[8];
#pragma unroll
    for (int i = 0; i < 8; ++i) acc[i] = (f32x4){0.f, 0.f, 0.f, 0.f};
#pragma unroll
    for (int ks = 0; ks < KS; ++ks) {
      s16x8 a;
      if constexpr (AF32) {
        const float* ap = (const float*)A0v + (size_t)arow * HID + ks * 32 + kb;
        float4 lo = *(const float4*)ap;
        float4 hi = *(const float4*)(ap + 4);
        i32x4 ai = {(int)pack2(lo.x, lo.y), (int)pack2(lo.z, lo.w),
                    (int)pack2(hi.x, hi.y), (int)pack2(hi.z, hi.w)};
        a = __builtin_bit_cast(s16x8, ai);
      } else if constexpr (DUAL) {
        const unsigned short* base = (ks < KS / 2) ? (const unsigned short*)A0v : A1;
        int kss = (ks < KS / 2) ? ks : ks - KS / 2;
        a = *(const s16x8*)(base + (size_t)arow * HID + kss * 32 + kb);
      } else {
        a = *(const s16x8*)((const unsigned short*)A0v + (size_t)arow * HID + ks * 32 + kb);
      }
#pragma unroll
      for (int nt = 0; nt < 8; ++nt)
        acc[nt] = __builtin_amdgcn_mfma_f32_16x16x32_bf16(a, breg[ks][nt], acc[nt], 0, 0, 0);
    }

    const int rbase = rt * 16 + (lane >> 4) * 4;
    if constexpr (MODE == 2) {
#pragma unroll
      for (int reg = 0; reg < 4; ++reg) {
        int row = rbase + reg;
        float dv = (float)deg[row];
        float v[8];
        float s = 0.f, s2 = 0.f;
#pragma unroll
        for (int nt = 0; nt < 8; ++nt) {
          float hv = bf2f(hres[(size_t)row * HID + nt * 16 + cl]);
          v[nt] = acc[nt][reg] + bs[nt] + dv * b2[nt] + hv;
          s += v[nt];
          s2 += v[nt] * v[nt];
        }
#pragma unroll
        for (int m = 1; m < 16; m <<= 1) {
          s += __shfl_xor(s, m);
          s2 += __shfl_xor(s2, m);
        }
        float mu = s * (1.f / 128.f);
        float var = s2 * (1.f / 128.f) - mu * mu;
        float inv = rsqrtf(var + EPS);
#pragma unroll
        for (int nt = 0; nt < 8; ++nt) {
          float o = (v[nt] - mu) * inv * gs[nt] + bes[nt];
          outB[(size_t)row * HID + nt * 16 + cl] = f2bf(o);
        }
      }
    } else {
#pragma unroll
      for (int reg = 0; reg < 4; ++reg) {
        int row = rbase + reg;
#pragma unroll
        for (int nt = 0; nt < 8; ++nt) {
          float vv = acc[nt][reg] + bs[nt];
          if constexpr (MODE == 0) outF[(size_t)row * outw + co + nt * 16 + cl] = vv;
          else outB[(size_t)row * outw + co + nt * 16 + cl] = f2bf(vv);
        }
      }
    }
  }
}

extern "C" void kernel_launch(void* const* d_in, const int* in_sizes, int n_in,
                              void* d_out, int out_size, void* d_ws, size_t ws_size,
                              hipStream_t stream) {
  const float* x     = (const float*)d_in[0];
  const int*   ei    = (const int*)d_in[1];
  const float* W_enc = (const float*)d_in[2];
  const float* b_enc = (const float*)d_in[3];
  const float* Wm1   = (const float*)d_in[4];
  const float* bm1   = (const float*)d_in[5];
  const float* Wm2   = (const float*)d_in[6];
  const float* bm2   = (const float*)d_in[7];
  const float* Wu    = (const float*)d_in[8];
  const float* bu    = (const float*)d_in[9];
  const float* gamma = (const float*)d_in[10];
  const float* beta  = (const float*)d_in[11];
  const float* W_out = (const float*)d_in[12];
  const float* b_out = (const float*)d_in[13];
  float* out = (float*)d_out;

  char* ws = (char*)d_ws;
  const size_t NBH = (size_t)N_NODES * HID * 2;  // 12.8 MB

  unsigned short* hb = (unsigned short*)(ws);            // [N][128] bf16
  unsigned short* pq = (unsigned short*)(ws + NBH);      // [N][256] bf16
  unsigned short* rb = (unsigned short*)(ws + 3 * NBH);  // [N][128] bf16
  char* wp = ws + 4 * NBH;
  unsigned short* Wenc_b = (unsigned short*)wp;          // 16384
  unsigned short* Wout_b = Wenc_b + 16384;               // 16384
  unsigned short* Wpq_b  = Wout_b + 16384;               // 2*32768
  unsigned short* Wcat_b = Wpq_b + 65536;                // 2*32768
  float*          bfold  = (float*)(Wcat_b + 65536);     // 256
  int* counts  = (int*)(bfold + 256);                    // [N] deg
  int* noff    = counts + N_NODES;                       // [N+1] exact CSR offsets
  int* boff    = noff + N_NODES + 1;                     // NBKT+1
  int* bcounts = boff + NBKT + 1;                        // NBKT
  int* bcursor = bcounts + NBKT;                         // NBKT
  unsigned int* esrc = (unsigned int*)(bcursor + NBKT);  // [E] src grouped by exact dst
  unsigned int* ebuf = (unsigned int*)(ws + NBH);        // [E] bucket-grouped (aliases pq;
                                                         //     dead before first pq write)

  // zero bucket counts, then prep weights || bucket hist
  hipMemsetAsync(bcounts, 0, NBKT * sizeof(int), stream);
  prep_hist_kernel<<<449 + 128, 256, 0, stream>>>(
      W_enc, W_out, Wm1, Wu, Wm2, bm2, (unsigned int*)Wenc_b, (unsigned int*)Wout_b,
      (unsigned int*)Wpq_b, Wcat_b, bfold, ei, bcounts);
  bscan_kernel<<<1, 1024, 0, stream>>>(bcounts, boff, bcursor);
  bscatter_kernel<<<128, 256, 0, stream>>>(ei, bcursor, ebuf);
  sort64_kernel<<<NBKT, 256, 0, stream>>>(ebuf, boff, esrc, noff, counts);

  // h = x @ W_enc.T + b_enc  -> bf16 hb
  gemm3<4, true, false, 1><<<512, 256, 0, stream>>>(
      x, nullptr, Wenc_b, b_enc, nullptr, nullptr, nullptr, nullptr, nullptr,
      nullptr, hb, HID);

  for (int l = 0; l < 2; ++l) {
    const unsigned short* Wpql  = Wpq_b + l * 32768;
    const unsigned short* Wcatl = Wcat_b + l * 32768;
    const float* bm1l = bm1 + l * HID;
    const float* bul  = bu + l * HID;
    const float* bfl  = bfold + l * HID;
    const float* gl   = gamma + l * HID;
    const float* bl   = beta + l * HID;

    // pq = h @ [Wm1a|Wm1b].T -> [N][256] bf16 (blockIdx.y halves)
    gemm3<4, false, false, 1><<<dim3(512, 2), 256, 0, stream>>>(
        hb, nullptr, Wpql, nullptr, nullptr, nullptr, nullptr, nullptr, nullptr,
        nullptr, pq, 256);
    // r = segsum(relu(p[src]+q[dst]+bm1)) over exact per-node runs (no atomics)
    aggregate3_kernel<<<6250, 256, 0, stream>>>((const unsigned int*)pq, bm1l, noff,
                                                esrc, (unsigned int*)rb);
    // h = LN(h + h@Wua.T + r@Wfold.T + deg*bfold + bu)*gamma+beta (in-place)
    gemm3<8, false, true, 2><<<256, 256, 0, stream>>>(
        hb, rb, Wcatl, bul, counts, bfl, gl, bl, hb, nullptr, hb, HID);
  }

  // out = h @ W_out.T + b_out (f32)
  gemm3<4, false, false, 0><<<512, 256, 0, stream>>>(
      hb, nullptr, Wout_b, b_out, nullptr, nullptr, nullptr, nullptr, nullptr,
      out, nullptr, HID);
}

// Round 9
// 221.983 us; speedup vs baseline: 6.9643x; 1.1410x over previous
//
#include <hip/hip_runtime.h>

#define N_NODES 50000
#define N_EDGES 800000
#define HID 128
#define EPS 1e-5f
#define NBKT 782            // ceil(50000/64) buckets of 64 dst nodes
#define ESLICE 3125         // edges per scatter/hist block (256 blocks)
#define NSLICE 256

typedef __attribute__((ext_vector_type(8))) short s16x8;   // 8 bf16 (4 VGPRs)
typedef __attribute__((ext_vector_type(4))) float f32x4;   // MFMA acc
typedef __attribute__((ext_vector_type(4))) int i32x4;

__device__ __forceinline__ unsigned short f2bf(float f) {  // RNE f32->bf16
  unsigned int u = __float_as_uint(f);
  u += 0x7fffu + ((u >> 16) & 1u);
  return (unsigned short)(u >> 16);
}
__device__ __forceinline__ unsigned int pack2(float a, float b) {
  return (unsigned int)f2bf(a) | ((unsigned int)f2bf(b) << 16);
}
__device__ __forceinline__ float bflo(unsigned int u) { return __uint_as_float(u << 16); }
__device__ __forceinline__ float bfhi(unsigned int u) { return __uint_as_float(u & 0xffff0000u); }
__device__ __forceinline__ float bf2f(unsigned short u) { return __uint_as_float((unsigned int)u << 16); }

// ================= weight prep (blocks 0..448)  ||  bucket hist (blocks 449..704) =================
__global__ __launch_bounds__(256) void prep_hist_kernel(
    const float* __restrict__ W_enc, const float* __restrict__ W_out,
    const float* __restrict__ Wm1, const float* __restrict__ Wu,
    const float* __restrict__ Wm2, const float* __restrict__ bm2,
    unsigned int* __restrict__ Wenc_b, unsigned int* __restrict__ Wout_b,
    unsigned int* __restrict__ Wpq_b, unsigned short* __restrict__ Wcat_b,
    float* __restrict__ bfold, const int* __restrict__ ei, int* __restrict__ bcounts) {
  __shared__ int lhist[NBKT];
  const int b = blockIdx.x, t = threadIdx.x;
  if (b >= 449) {  // ---- bucket histogram ----
    const int e0 = (b - 449) * ESLICE;
    for (int i = t; i < NBKT; i += 256) lhist[i] = 0;
    __syncthreads();
    for (int e = e0 + t; e < e0 + ESLICE; e += 256)
      atomicAdd(&lhist[ei[N_EDGES + e] >> 6], 1);
    __syncthreads();
    for (int i = t; i < NBKT; i += 256)
      if (lhist[i]) atomicAdd(&bcounts[i], lhist[i]);
    return;
  }
  if (b < 32) {            // W_enc: 8192 uints
    int i = b * 256 + t;
    Wenc_b[i] = pack2(W_enc[2 * i], W_enc[2 * i + 1]);
  } else if (b < 64) {     // W_out
    int i = (b - 32) * 256 + t;
    Wout_b[i] = pack2(W_out[2 * i], W_out[2 * i + 1]);
  } else if (b < 192) {    // repack Wm1 -> Wpq [l][256 rows][128 k]
    int i = (b - 64) * 256 + t;  // 32768
    int k2 = i & 63;
    int c = (i >> 6) & 255;
    int l = i >> 14;
    const float* srow = Wm1 + ((size_t)l * 128 + (c & 127)) * 256 + ((c >> 7) << 7);
    Wpq_b[i] = pack2(srow[2 * k2], srow[2 * k2 + 1]);
  } else if (b < 448) {    // Wcat: [l][128 rows][256 k], hi-k = Wu_b @ Wm2 fold
    int i = (b - 192) * 256 + t;  // 65536
    int k = i & 255, c = (i >> 8) & 127, l = i >> 15;
    const float* wrow = Wu + ((size_t)l * 128 + c) * 256;
    float v;
    if (k < 128) {
      v = wrow[k];
    } else {
      const float* wb = wrow + 128;
      const float* m2 = Wm2 + (size_t)l * 128 * 128 + (k - 128);
      float s = 0.f;
      for (int j = 0; j < 128; ++j) s += wb[j] * m2[(size_t)j * 128];
      v = s;
    }
    Wcat_b[i] = f2bf(v);
  } else {                 // bfold[l][c] = Wu_b[l][c][:] . bm2[l]
    int l = t >> 7, c = t & 127;
    const float* wb = Wu + ((size_t)l * 128 + c) * 256 + 128;
    const float* bv = bm2 + l * 128;
    float s = 0.f;
    for (int j = 0; j < 128; ++j) s += wb[j] * bv[j];
    bfold[t] = s;
  }
}

// ================= bucket scan: one block, one pass (NBKT=782 < 1024) =================
__global__ __launch_bounds__(1024) void bscan_kernel(const int* __restrict__ bcounts,
                                                     int* __restrict__ boff,
                                                     int* __restrict__ bcursor) {
  __shared__ int wtot[16];
  const int t = threadIdx.x, lane = t & 63, w = t >> 6;
  int v = (t < NBKT) ? bcounts[t] : 0;
  int s = v;
#pragma unroll
  for (int off = 1; off < 64; off <<= 1) {
    int tt = __shfl_up(s, off);
    if (lane >= off) s += tt;
  }
  if (lane == 63) wtot[w] = s;
  __syncthreads();
  int woff = 0;
#pragma unroll
  for (int j = 0; j < 16; ++j) { int tv = wtot[j]; if (j < w) woff += tv; }
  int excl = woff + (s - v);
  if (t < NBKT) { boff[t] = excl; bcursor[t] = excl; }
  if (t == NBKT) boff[NBKT] = excl;  // v=0 here -> excl == total
}

// ================= bucket scatter: 2-pass LDS counting sort per 3125-edge slice =================
// staged word: src (0..15) | dst_local (16..21) | bucket (22..31).
// Flush is thread-per-element (independent iterations), coalescing within bucket runs.
__global__ __launch_bounds__(256) void bscatter_kernel(const int* __restrict__ ei,
                                                       int* __restrict__ bcursor,
                                                       unsigned int* __restrict__ ebuf) {
  __shared__ int lhist[784];
  __shared__ int lstart[784];
  __shared__ int lcur[784];
  __shared__ int gbase[784];
  __shared__ unsigned int staged[ESLICE];
  __shared__ int wtot[4];
  const int t = threadIdx.x, lane = t & 63, w = t >> 6;
  const int e0 = blockIdx.x * ESLICE;

  for (int i = t; i < 784; i += 256) lhist[i] = 0;
  __syncthreads();
  for (int e = e0 + t; e < e0 + ESLICE; e += 256)
    atomicAdd(&lhist[ei[N_EDGES + e] >> 6], 1);
  __syncthreads();

  // local exclusive scan over buckets: thread t owns 4t..4t+3 (t<196)
  int tsum = 0;
  if (t < 196) tsum = lhist[4 * t] + lhist[4 * t + 1] + lhist[4 * t + 2] + lhist[4 * t + 3];
  int inc = tsum;
#pragma unroll
  for (int off = 1; off < 64; off <<= 1) {
    int tt = __shfl_up(inc, off);
    if (lane >= off) inc += tt;
  }
  if (lane == 63) wtot[w] = inc;
  __syncthreads();
  int woff = 0;
#pragma unroll
  for (int j = 0; j < 4; ++j) { int tv = wtot[j]; if (j < w) woff += tv; }
  if (t < 196) {
    int run = woff + inc - tsum;
#pragma unroll
    for (int j = 0; j < 4; ++j) {
      lstart[4 * t + j] = run;
      lcur[4 * t + j] = run;
      run += lhist[4 * t + j];
    }
  }
  // reserve global ranges (independent atomics, pipelined)
  for (int bk = t; bk < NBKT; bk += 256)
    gbase[bk] = lhist[bk] ? atomicAdd(&bcursor[bk], lhist[bk]) : 0;
  __syncthreads();

  // pass 2: place into staged, grouped by bucket; bucket id rides in bits 22+
  for (int e = e0 + t; e < e0 + ESLICE; e += 256) {
    int s = ei[e], d = ei[N_EDGES + e];
    int pos = atomicAdd(&lcur[d >> 6], 1);
    staged[pos] = (unsigned int)s | ((unsigned int)(d & 63) << 16) |
                  ((unsigned int)(d >> 6) << 22);
  }
  __syncthreads();

  // flush: one thread per element, independent
  for (int i = t; i < ESLICE; i += 256) {
    unsigned int pk = staged[i];
    int bk = pk >> 22;
    ebuf[gbase[bk] + (i - lstart[bk])] = pk;
  }
}

// ================= sort64: bucket -> exact per-node CSR (no FP atomics anywhere) =================
__global__ __launch_bounds__(256) void sort64_kernel(const unsigned int* __restrict__ ebuf,
                                                     const int* __restrict__ boff,
                                                     unsigned int* __restrict__ esrc,
                                                     int* __restrict__ noff,
                                                     int* __restrict__ counts) {
  __shared__ int hist[64];
  __shared__ int lcur[64];
  const int b = blockIdx.x, t = threadIdx.x;
  const int e0 = boff[b], e1 = boff[b + 1];
  if (t < 64) hist[t] = 0;
  __syncthreads();
  for (int e = e0 + t; e < e1; e += 256)
    atomicAdd(&hist[(ebuf[e] >> 16) & 63], 1);
  __syncthreads();
  if (t < 64) {  // wave 0: exclusive scan of 64 bins
    int v = hist[t];
    int s = v;
#pragma unroll
    for (int off = 1; off < 64; off <<= 1) {
      int tt = __shfl_up(s, off);
      if (t >= off) s += tt;
    }
    lcur[t] = s - v;
    int node = b * 64 + t;
    if (node < N_NODES) {
      noff[node] = e0 + s - v;
      counts[node] = v;
    }
  }
  __syncthreads();
  for (int e = e0 + t; e < e1; e += 256) {
    unsigned int pk = ebuf[e];
    int pos = atomicAdd(&lcur[(pk >> 16) & 63], 1);
    esrc[e0 + pos] = pk & 0xffffu;
  }
  if (b == NBKT - 1 && t == 0) noff[N_NODES] = e1;
}

// ================= aggregation: wave per node, 2 edges/iter, unroll 4 =================
// r[n] = sum_{e: dst=n} relu(p[src] + q[n] + bm1)
__global__ __launch_bounds__(256) void aggregate4_kernel(
    const unsigned int* __restrict__ pq32, const float* __restrict__ bm1,
    const int* __restrict__ noff, const unsigned int* __restrict__ esrc,
    unsigned int* __restrict__ rb32) {
  const int node = blockIdx.x * 4 + (threadIdx.x >> 6);
  const int lane = threadIdx.x & 63;
  const int l = lane & 31;   // channel-pair index (channels 4l..4l+3)
  const int eh = lane >> 5;  // which edge of the wave's pair
  uint2 qv = *(const uint2*)(pq32 + (size_t)node * 128 + 64 + 2 * l);
  float4 bv = *(const float4*)(bm1 + 4 * l);
  float q0 = bflo(qv.x) + bv.x, q1 = bfhi(qv.x) + bv.y;
  float q2 = bflo(qv.y) + bv.z, q3 = bfhi(qv.y) + bv.w;
  float a0 = 0.f, a1 = 0.f, a2 = 0.f, a3 = 0.f;
  const int i0 = noff[node], i1 = noff[node + 1];
  const int nfull = (i1 - i0) >> 3;  // 8 edges per full wave-iter
  int idx = i0 + eh;
  for (int j = 0; j < nfull; ++j, idx += 8) {
    int s0 = esrc[idx], s1 = esrc[idx + 2], s2 = esrc[idx + 4], s3 = esrc[idx + 6];
    uint2 u0 = *(const uint2*)(pq32 + (size_t)s0 * 128 + 2 * l);
    uint2 u1 = *(const uint2*)(pq32 + (size_t)s1 * 128 + 2 * l);
    uint2 u2 = *(const uint2*)(pq32 + (size_t)s2 * 128 + 2 * l);
    uint2 u3 = *(const uint2*)(pq32 + (size_t)s3 * 128 + 2 * l);
    a0 += fmaxf(bflo(u0.x) + q0, 0.f) + fmaxf(bflo(u1.x) + q0, 0.f) +
          fmaxf(bflo(u2.x) + q0, 0.f) + fmaxf(bflo(u3.x) + q0, 0.f);
    a1 += fmaxf(bfhi(u0.x) + q1, 0.f) + fmaxf(bfhi(u1.x) + q1, 0.f) +
          fmaxf(bfhi(u2.x) + q1, 0.f) + fmaxf(bfhi(u3.x) + q1, 0.f);
    a2 += fmaxf(bflo(u0.y) + q2, 0.f) + fmaxf(bflo(u1.y) + q2, 0.f) +
          fmaxf(bflo(u2.y) + q2, 0.f) + fmaxf(bflo(u3.y) + q2, 0.f);
    a3 += fmaxf(bfhi(u0.y) + q3, 0.f) + fmaxf(bfhi(u1.y) + q3, 0.f) +
          fmaxf(bfhi(u2.y) + q3, 0.f) + fmaxf(bfhi(u3.y) + q3, 0.f);
  }
  for (; idx < i1; idx += 2) {  // tail: <8 edges, split across the two halves
    uint2 u0 = *(const uint2*)(pq32 + (size_t)esrc[idx] * 128 + 2 * l);
    a0 += fmaxf(bflo(u0.x) + q0, 0.f);
    a1 += fmaxf(bfhi(u0.x) + q1, 0.f);
    a2 += fmaxf(bflo(u0.y) + q2, 0.f);
    a3 += fmaxf(bfhi(u0.y) + q3, 0.f);
  }
  a0 += __shfl_xor(a0, 32);
  a1 += __shfl_xor(a1, 32);
  a2 += __shfl_xor(a2, 32);
  a3 += __shfl_xor(a3, 32);
  if (lane < 32) {
    uint2 r;
    r.x = pack2(a0, a1);
    r.y = pack2(a2, a3);
    *(uint2*)(rb32 + (size_t)node * 64 + 2 * l) = r;
  }
}

// ================= persistent-B MFMA GEMM (unchanged) =================
template <int KS, bool AF32, bool DUAL, int MODE>
__global__ __launch_bounds__(256, DUAL ? 1 : 2) void gemm3(
    const void* __restrict__ A0v, const unsigned short* __restrict__ A1,
    const unsigned short* __restrict__ W, const float* __restrict__ bias,
    const int* __restrict__ deg, const float* __restrict__ bias2,
    const float* __restrict__ gamma, const float* __restrict__ beta,
    const unsigned short* __restrict__ hres, float* __restrict__ outF,
    unsigned short* __restrict__ outB, int outw) {
  constexpr int KW = KS * 32;
  constexpr int NFRAG = KS * 8;
  __shared__ short Bs[NFRAG * 512];
  const int lane = threadIdx.x & 63;
  const int w = threadIdx.x >> 6;
  const int cl = lane & 15;
  const int kb = (lane >> 4) * 8;
  const int co = blockIdx.y * 128;
  W += (size_t)blockIdx.y * 128 * KW;

  for (int f = w; f < NFRAG; f += 4) {
    int nt = f & 7, ks = f >> 3;
    s16x8 bv = *(const s16x8*)(W + (size_t)(nt * 16 + cl) * KW + ks * 32 + kb);
    *(s16x8*)(Bs + f * 512 + lane * 8) = bv;
  }
  __syncthreads();

  s16x8 breg[KS][8];
#pragma unroll
  for (int ks = 0; ks < KS; ++ks)
#pragma unroll
    for (int nt = 0; nt < 8; ++nt)
      breg[ks][nt] = *(const s16x8*)(Bs + (ks * 8 + nt) * 512 + lane * 8);

  float bs[8], b2[8], gs[8], bes[8];
#pragma unroll
  for (int nt = 0; nt < 8; ++nt) {
    int col = nt * 16 + cl;
    bs[nt] = bias ? bias[col] : 0.f;
    if constexpr (MODE == 2) {
      b2[nt] = bias2[col];
      gs[nt] = gamma[col];
      bes[nt] = beta[col];
    }
  }

  const int step = gridDim.x * 4;
  for (int rt = blockIdx.x * 4 + w; rt < 3125; rt += step) {  // 3125*16 == 50000
    const int arow = rt * 16 + cl;
    f32x4 acc[8];
#pragma unroll
    for (int i = 0; i < 8; ++i) acc[i] = (f32x4){0.f, 0.f, 0.f, 0.f};
#pragma unroll
    for (int ks = 0; ks < KS; ++ks) {
      s16x8 a;
      if constexpr (AF32) {
        const float* ap = (const float*)A0v + (size_t)arow * HID + ks * 32 + kb;
        float4 lo = *(const float4*)ap;
        float4 hi = *(const float4*)(ap + 4);
        i32x4 ai = {(int)pack2(lo.x, lo.y), (int)pack2(lo.z, lo.w),
                    (int)pack2(hi.x, hi.y), (int)pack2(hi.z, hi.w)};
        a = __builtin_bit_cast(s16x8, ai);
      } else if constexpr (DUAL) {
        const unsigned short* base = (ks < KS / 2) ? (const unsigned short*)A0v : A1;
        int kss = (ks < KS / 2) ? ks : ks - KS / 2;
        a = *(const s16x8*)(base + (size_t)arow * HID + kss * 32 + kb);
      } else {
        a = *(const s16x8*)((const unsigned short*)A0v + (size_t)arow * HID + ks * 32 + kb);
      }
#pragma unroll
      for (int nt = 0; nt < 8; ++nt)
        acc[nt] = __builtin_amdgcn_mfma_f32_16x16x32_bf16(a, breg[ks][nt], acc[nt], 0, 0, 0);
    }

    const int rbase = rt * 16 + (lane >> 4) * 4;
    if constexpr (MODE == 2) {
#pragma unroll
      for (int reg = 0; reg < 4; ++reg) {
        int row = rbase + reg;
        float dv = (float)deg[row];
        float v[8];
        float s = 0.f, s2 = 0.f;
#pragma unroll
        for (int nt = 0; nt < 8; ++nt) {
          float hv = bf2f(hres[(size_t)row * HID + nt * 16 + cl]);
          v[nt] = acc[nt][reg] + bs[nt] + dv * b2[nt] + hv;
          s += v[nt];
          s2 += v[nt] * v[nt];
        }
#pragma unroll
        for (int m = 1; m < 16; m <<= 1) {
          s += __shfl_xor(s, m);
          s2 += __shfl_xor(s2, m);
        }
        float mu = s * (1.f / 128.f);
        float var = s2 * (1.f / 128.f) - mu * mu;
        float inv = rsqrtf(var + EPS);
#pragma unroll
        for (int nt = 0; nt < 8; ++nt) {
          float o = (v[nt] - mu) * inv * gs[nt] + bes[nt];
          outB[(size_t)row * HID + nt * 16 + cl] = f2bf(o);
        }
      }
    } else {
#pragma unroll
      for (int reg = 0; reg < 4; ++reg) {
        int row = rbase + reg;
#pragma unroll
        for (int nt = 0; nt < 8; ++nt) {
          float vv = acc[nt][reg] + bs[nt];
          if constexpr (MODE == 0) outF[(size_t)row * outw + co + nt * 16 + cl] = vv;
          else outB[(size_t)row * outw + co + nt * 16 + cl] = f2bf(vv);
        }
      }
    }
  }
}

extern "C" void kernel_launch(void* const* d_in, const int* in_sizes, int n_in,
                              void* d_out, int out_size, void* d_ws, size_t ws_size,
                              hipStream_t stream) {
  const float* x     = (const float*)d_in[0];
  const int*   ei    = (const int*)d_in[1];
  const float* W_enc = (const float*)d_in[2];
  const float* b_enc = (const float*)d_in[3];
  const float* Wm1   = (const float*)d_in[4];
  const float* bm1   = (const float*)d_in[5];
  const float* Wm2   = (const float*)d_in[6];
  const float* bm2   = (const float*)d_in[7];
  const float* Wu    = (const float*)d_in[8];
  const float* bu    = (const float*)d_in[9];
  const float* gamma = (const float*)d_in[10];
  const float* beta  = (const float*)d_in[11];
  const float* W_out = (const float*)d_in[12];
  const float* b_out = (const float*)d_in[13];
  float* out = (float*)d_out;

  char* ws = (char*)d_ws;
  const size_t NBH = (size_t)N_NODES * HID * 2;  // 12.8 MB

  unsigned short* hb = (unsigned short*)(ws);            // [N][128] bf16
  unsigned short* pq = (unsigned short*)(ws + NBH);      // [N][256] bf16
  unsigned short* rb = (unsigned short*)(ws + 3 * NBH);  // [N][128] bf16
  char* wp = ws + 4 * NBH;
  unsigned short* Wenc_b = (unsigned short*)wp;          // 16384
  unsigned short* Wout_b = Wenc_b + 16384;               // 16384
  unsigned short* Wpq_b  = Wout_b + 16384;               // 2*32768
  unsigned short* Wcat_b = Wpq_b + 65536;                // 2*32768
  float*          bfold  = (float*)(Wcat_b + 65536);     // 256
  int* counts  = (int*)(bfold + 256);                    // [N] deg
  int* noff    = counts + N_NODES;                       // [N+1] exact CSR offsets
  int* boff    = noff + N_NODES + 1;                     // NBKT+1
  int* bcounts = boff + NBKT + 1;                        // NBKT
  int* bcursor = bcounts + NBKT;                         // NBKT
  unsigned int* esrc = (unsigned int*)(bcursor + NBKT);  // [E] src grouped by exact dst
  unsigned int* ebuf = (unsigned int*)(ws + NBH);        // [E] bucket-grouped (aliases pq;
                                                         //     dead before first pq write)

  // zero bucket counts, then prep weights || bucket hist
  hipMemsetAsync(bcounts, 0, NBKT * sizeof(int), stream);
  prep_hist_kernel<<<449 + NSLICE, 256, 0, stream>>>(
      W_enc, W_out, Wm1, Wu, Wm2, bm2, (unsigned int*)Wenc_b, (unsigned int*)Wout_b,
      (unsigned int*)Wpq_b, Wcat_b, bfold, ei, bcounts);
  bscan_kernel<<<1, 1024, 0, stream>>>(bcounts, boff, bcursor);
  bscatter_kernel<<<NSLICE, 256, 0, stream>>>(ei, bcursor, ebuf);
  sort64_kernel<<<NBKT, 256, 0, stream>>>(ebuf, boff, esrc, noff, counts);

  // h = x @ W_enc.T + b_enc  -> bf16 hb
  gemm3<4, true, false, 1><<<512, 256, 0, stream>>>(
      x, nullptr, Wenc_b, b_enc, nullptr, nullptr, nullptr, nullptr, nullptr,
      nullptr, hb, HID);

  for (int l = 0; l < 2; ++l) {
    const unsigned short* Wpql  = Wpq_b + l * 32768;
    const unsigned short* Wcatl = Wcat_b + l * 32768;
    const float* bm1l = bm1 + l * HID;
    const float* bul  = bu + l * HID;
    const float* bfl  = bfold + l * HID;
    const float* gl   = gamma + l * HID;
    const float* bl   = beta + l * HID;

    // pq = h @ [Wm1a|Wm1b].T -> [N][256] bf16 (blockIdx.y halves)
    gemm3<4, false, false, 1><<<dim3(512, 2), 256, 0, stream>>>(
        hb, nullptr, Wpql, nullptr, nullptr, nullptr, nullptr, nullptr, nullptr,
        nullptr, pq, 256);
    // r = segsum(relu(p[src]+q[dst]+bm1)) over exact per-node runs (no atomics)
    aggregate4_kernel<<<12500, 256, 0, stream>>>((const unsigned int*)pq, bm1l, noff,
                                                 esrc, (unsigned int*)rb);
    // h = LN(h + h@Wua.T + r@Wfold.T + deg*bfold + bu)*gamma+beta (in-place)
    gemm3<8, false, true, 2><<<256, 256, 0, stream>>>(
        hb, rb, Wcatl, bul, counts, bfl, gl, bl, hb, nullptr, hb, HID);
  }

  // out = h @ W_out.T + b_out (f32)
  gemm3<4, false, false, 0><<<512, 256, 0, stream>>>(
      hb, nullptr, Wout_b, b_out, nullptr, nullptr, nullptr, nullptr, nullptr,
      out, nullptr, HID);
}

// Round 10
// 205.307 us; speedup vs baseline: 7.5300x; 1.0812x over previous
//
#include <hip/hip_runtime.h>

#define N_NODES 50000
#define N_EDGES 800000
#define HID 128
#define EPS 1e-5f
#define NBKT 782            // ceil(50000/64) buckets of 64 dst nodes
#define ESLICE 3125         // edges per scatter/hist block (256 blocks)
#define NSLICE 256

typedef __attribute__((ext_vector_type(8))) short s16x8;   // 8 bf16 (4 VGPRs)
typedef __attribute__((ext_vector_type(4))) float f32x4;   // MFMA acc
typedef __attribute__((ext_vector_type(4))) int i32x4;

__device__ __forceinline__ unsigned short f2bf(float f) {  // RNE f32->bf16
  unsigned int u = __float_as_uint(f);
  u += 0x7fffu + ((u >> 16) & 1u);
  return (unsigned short)(u >> 16);
}
__device__ __forceinline__ unsigned int pack2(float a, float b) {
  return (unsigned int)f2bf(a) | ((unsigned int)f2bf(b) << 16);
}
__device__ __forceinline__ float bflo(unsigned int u) { return __uint_as_float(u << 16); }
__device__ __forceinline__ float bfhi(unsigned int u) { return __uint_as_float(u & 0xffff0000u); }
__device__ __forceinline__ float bf2f(unsigned short u) { return __uint_as_float((unsigned int)u << 16); }

// ================= weight prep (blocks 0..448)  ||  bucket hist (blocks 449..704) =================
// hist blocks write private shist rows (plain stores) -> no global atomics, no memset needed.
__global__ __launch_bounds__(256) void prep_hist_kernel(
    const float* __restrict__ W_enc, const float* __restrict__ W_out,
    const float* __restrict__ Wm1, const float* __restrict__ Wu,
    const float* __restrict__ Wm2, const float* __restrict__ bm2,
    unsigned int* __restrict__ Wenc_b, unsigned int* __restrict__ Wout_b,
    unsigned int* __restrict__ Wpq_b, unsigned short* __restrict__ Wcat_b,
    float* __restrict__ bfold, const int* __restrict__ ei, int* __restrict__ shist) {
  __shared__ int lhist[NBKT];
  const int b = blockIdx.x, t = threadIdx.x;
  if (b >= 449) {  // ---- bucket histogram (one slice per block) ----
    const int sl = b - 449;
    const int e0 = sl * ESLICE;
    for (int i = t; i < NBKT; i += 256) lhist[i] = 0;
    __syncthreads();
    for (int e = e0 + t; e < e0 + ESLICE; e += 256)
      atomicAdd(&lhist[ei[N_EDGES + e] >> 6], 1);
    __syncthreads();
    for (int i = t; i < NBKT; i += 256) shist[sl * NBKT + i] = lhist[i];
    return;
  }
  if (b < 32) {            // W_enc: 8192 uints
    int i = b * 256 + t;
    Wenc_b[i] = pack2(W_enc[2 * i], W_enc[2 * i + 1]);
  } else if (b < 64) {     // W_out
    int i = (b - 32) * 256 + t;
    Wout_b[i] = pack2(W_out[2 * i], W_out[2 * i + 1]);
  } else if (b < 192) {    // repack Wm1 -> Wpq [l][256 rows][128 k]
    int i = (b - 64) * 256 + t;  // 32768
    int k2 = i & 63;
    int c = (i >> 6) & 255;
    int l = i >> 14;
    const float* srow = Wm1 + ((size_t)l * 128 + (c & 127)) * 256 + ((c >> 7) << 7);
    Wpq_b[i] = pack2(srow[2 * k2], srow[2 * k2 + 1]);
  } else if (b < 448) {    // Wcat: [l][128 rows][256 k], hi-k = Wu_b @ Wm2 fold
    int i = (b - 192) * 256 + t;  // 65536
    int k = i & 255, c = (i >> 8) & 127, l = i >> 15;
    const float* wrow = Wu + ((size_t)l * 128 + c) * 256;
    float v;
    if (k < 128) {
      v = wrow[k];
    } else {
      const float* wb = wrow + 128;
      const float* m2 = Wm2 + (size_t)l * 128 * 128 + (k - 128);
      float s = 0.f;
      for (int j = 0; j < 128; ++j) s += wb[j] * m2[(size_t)j * 128];
      v = s;
    }
    Wcat_b[i] = f2bf(v);
  } else {                 // bfold[l][c] = Wu_b[l][c][:] . bm2[l]
    int l = t >> 7, c = t & 127;
    const float* wb = Wu + ((size_t)l * 128 + c) * 256 + 128;
    const float* bv = bm2 + l * 128;
    float s = 0.f;
    for (int j = 0; j < 128; ++j) s += wb[j] * bv[j];
    bfold[t] = s;
  }
}

// ================= column-sum of slice histograms -> bcounts (no atomics, no memset) =========
__global__ __launch_bounds__(256) void colsum_kernel(const int* __restrict__ shist,
                                                     int* __restrict__ bcounts) {
  int b = blockIdx.x * 256 + threadIdx.x;
  if (b >= NBKT) return;
  int s = 0;
  for (int j = 0; j < NSLICE; ++j) s += shist[j * NBKT + b];  // coalesced across threads
  bcounts[b] = s;
}

// ================= bucket scan: one block, one pass (NBKT=782 < 1024) =================
__global__ __launch_bounds__(1024) void bscan_kernel(const int* __restrict__ bcounts,
                                                     int* __restrict__ boff,
                                                     int* __restrict__ bcursor) {
  __shared__ int wtot[16];
  const int t = threadIdx.x, lane = t & 63, w = t >> 6;
  int v = (t < NBKT) ? bcounts[t] : 0;
  int s = v;
#pragma unroll
  for (int off = 1; off < 64; off <<= 1) {
    int tt = __shfl_up(s, off);
    if (lane >= off) s += tt;
  }
  if (lane == 63) wtot[w] = s;
  __syncthreads();
  int woff = 0;
#pragma unroll
  for (int j = 0; j < 16; ++j) { int tv = wtot[j]; if (j < w) woff += tv; }
  int excl = woff + (s - v);
  if (t < NBKT) { boff[t] = excl; bcursor[t] = excl; }
  if (t == NBKT) boff[NBKT] = excl;  // v=0 here -> excl == total
}

// ================= device-fn bodies for merged kernels =================
struct BscatSmem {
  int lhist[784], lstart[784], lcur[784], gbase[784];
  unsigned int staged[ESLICE];
  int wtot[4];
};
struct Sort64Smem { int hist[64]; int lcur[64]; };

// bucket scatter: 2-pass LDS counting sort per 3125-edge slice.
// staged word: src (0..15) | dst_local (16..21) | bucket (22..31). Thread-per-element flush.
__device__ __forceinline__ void bscatter_dev(BscatSmem& sm, const int* ei, int* bcursor,
                                             unsigned int* ebuf, int bx) {
  const int t = threadIdx.x, lane = t & 63, w = t >> 6;
  const int e0 = bx * ESLICE;

  for (int i = t; i < 784; i += 256) sm.lhist[i] = 0;
  __syncthreads();
  for (int e = e0 + t; e < e0 + ESLICE; e += 256)
    atomicAdd(&sm.lhist[ei[N_EDGES + e] >> 6], 1);
  __syncthreads();

  int tsum = 0;
  if (t < 196)
    tsum = sm.lhist[4 * t] + sm.lhist[4 * t + 1] + sm.lhist[4 * t + 2] + sm.lhist[4 * t + 3];
  int inc = tsum;
#pragma unroll
  for (int off = 1; off < 64; off <<= 1) {
    int tt = __shfl_up(inc, off);
    if (lane >= off) inc += tt;
  }
  if (lane == 63) sm.wtot[w] = inc;
  __syncthreads();
  int woff = 0;
#pragma unroll
  for (int j = 0; j < 4; ++j) { int tv = sm.wtot[j]; if (j < w) woff += tv; }
  if (t < 196) {
    int run = woff + inc - tsum;
#pragma unroll
    for (int j = 0; j < 4; ++j) {
      sm.lstart[4 * t + j] = run;
      sm.lcur[4 * t + j] = run;
      run += sm.lhist[4 * t + j];
    }
  }
  for (int bk = t; bk < NBKT; bk += 256)
    sm.gbase[bk] = sm.lhist[bk] ? atomicAdd(&bcursor[bk], sm.lhist[bk]) : 0;
  __syncthreads();

  for (int e = e0 + t; e < e0 + ESLICE; e += 256) {
    int s = ei[e], d = ei[N_EDGES + e];
    int pos = atomicAdd(&sm.lcur[d >> 6], 1);
    sm.staged[pos] = (unsigned int)s | ((unsigned int)(d & 63) << 16) |
                     ((unsigned int)(d >> 6) << 22);
  }
  __syncthreads();

  for (int i = t; i < ESLICE; i += 256) {
    unsigned int pk = sm.staged[i];
    int bk = pk >> 22;
    ebuf[sm.gbase[bk] + (i - sm.lstart[bk])] = pk;
  }
}

// sort64: bucket -> exact per-node CSR; esrc stored as u16 (src < 65536).
__device__ __forceinline__ void sort64_dev(Sort64Smem& sm, const unsigned int* ebuf,
                                           const int* boff, unsigned short* esrc,
                                           int* noff, int* counts, int b) {
  const int t = threadIdx.x;
  const int e0 = boff[b], e1 = boff[b + 1];
  if (t < 64) sm.hist[t] = 0;
  __syncthreads();
  for (int e = e0 + t; e < e1; e += 256)
    atomicAdd(&sm.hist[(ebuf[e] >> 16) & 63], 1);
  __syncthreads();
  if (t < 64) {
    int v = sm.hist[t];
    int s = v;
#pragma unroll
    for (int off = 1; off < 64; off <<= 1) {
      int tt = __shfl_up(s, off);
      if (t >= off) s += tt;
    }
    sm.lcur[t] = s - v;
    int node = b * 64 + t;
    if (node < N_NODES) {
      noff[node] = e0 + s - v;
      counts[node] = v;
    }
  }
  __syncthreads();
  for (int e = e0 + t; e < e1; e += 256) {
    unsigned int pk = ebuf[e];
    int pos = atomicAdd(&sm.lcur[(pk >> 16) & 63], 1);
    esrc[e0 + pos] = (unsigned short)(pk & 0xffffu);
  }
  if (b == NBKT - 1 && t == 0) noff[N_NODES] = e1;
}

// ================= persistent-B MFMA GEMM body =================
template <int KS, bool AF32, bool DUAL, int MODE>
__device__ __forceinline__ void gemm3_dev(
    short* Bs, int bx, int gx, int by,
    const void* A0v, const unsigned short* A1,
    const unsigned short* W, const float* bias,
    const int* deg, const float* bias2,
    const float* gamma, const float* beta,
    const unsigned short* hres, float* outF,
    unsigned short* outB, int outw) {
  constexpr int KW = KS * 32;
  constexpr int NFRAG = KS * 8;
  const int lane = threadIdx.x & 63;
  const int w = threadIdx.x >> 6;
  const int cl = lane & 15;
  const int kb = (lane >> 4) * 8;
  const int co = by * 128;
  W += (size_t)by * 128 * KW;

  for (int f = w; f < NFRAG; f += 4) {
    int nt = f & 7, ks = f >> 3;
    s16x8 bv = *(const s16x8*)(W + (size_t)(nt * 16 + cl) * KW + ks * 32 + kb);
    *(s16x8*)(Bs + f * 512 + lane * 8) = bv;
  }
  __syncthreads();

  s16x8 breg[KS][8];
#pragma unroll
  for (int ks = 0; ks < KS; ++ks)
#pragma unroll
    for (int nt = 0; nt < 8; ++nt)
      breg[ks][nt] = *(const s16x8*)(Bs + (ks * 8 + nt) * 512 + lane * 8);

  float bs[8], b2[8], gs[8], bes[8];
#pragma unroll
  for (int nt = 0; nt < 8; ++nt) {
    int col = nt * 16 + cl;
    bs[nt] = bias ? bias[col] : 0.f;
    if constexpr (MODE == 2) {
      b2[nt] = bias2[col];
      gs[nt] = gamma[col];
      bes[nt] = beta[col];
    }
  }

  const int step = gx * 4;
  for (int rt = bx * 4 + w; rt < 3125; rt += step) {  // 3125*16 == 50000
    const int arow = rt * 16 + cl;
    f32x4 acc[8];
#pragma unroll
    for (int i = 0; i < 8; ++i) acc[i] = (f32x4){0.f, 0.f, 0.f, 0.f};
#pragma unroll
    for (int ks = 0; ks < KS; ++ks) {
      s16x8 a;
      if constexpr (AF32) {
        const float* ap = (const float*)A0v + (size_t)arow * HID + ks * 32 + kb;
        float4 lo = *(const float4*)ap;
        float4 hi = *(const float4*)(ap + 4);
        i32x4 ai = {(int)pack2(lo.x, lo.y), (int)pack2(lo.z, lo.w),
                    (int)pack2(hi.x, hi.y), (int)pack2(hi.z, hi.w)};
        a = __builtin_bit_cast(s16x8, ai);
      } else if constexpr (DUAL) {
        const unsigned short* base = (ks < KS / 2) ? (const unsigned short*)A0v : A1;
        int kss = (ks < KS / 2) ? ks : ks - KS / 2;
        a = *(const s16x8*)(base + (size_t)arow * HID + kss * 32 + kb);
      } else {
        a = *(const s16x8*)((const unsigned short*)A0v + (size_t)arow * HID + ks * 32 + kb);
      }
#pragma unroll
      for (int nt = 0; nt < 8; ++nt)
        acc[nt] = __builtin_amdgcn_mfma_f32_16x16x32_bf16(a, breg[ks][nt], acc[nt], 0, 0, 0);
    }

    const int rbase = rt * 16 + (lane >> 4) * 4;
    if constexpr (MODE == 2) {
#pragma unroll
      for (int reg = 0; reg < 4; ++reg) {
        int row = rbase + reg;
        float dv = (float)deg[row];
        float v[8];
        float s = 0.f, s2 = 0.f;
#pragma unroll
        for (int nt = 0; nt < 8; ++nt) {
          float hv = bf2f(hres[(size_t)row * HID + nt * 16 + cl]);
          v[nt] = acc[nt][reg] + bs[nt] + dv * b2[nt] + hv;
          s += v[nt];
          s2 += v[nt] * v[nt];
        }
#pragma unroll
        for (int m = 1; m < 16; m <<= 1) {
          s += __shfl_xor(s, m);
          s2 += __shfl_xor(s2, m);
        }
        float mu = s * (1.f / 128.f);
        float var = s2 * (1.f / 128.f) - mu * mu;
        float inv = rsqrtf(var + EPS);
#pragma unroll
        for (int nt = 0; nt < 8; ++nt) {
          float o = (v[nt] - mu) * inv * gs[nt] + bes[nt];
          outB[(size_t)row * HID + nt * 16 + cl] = f2bf(o);
        }
      }
    } else {
#pragma unroll
      for (int reg = 0; reg < 4; ++reg) {
        int row = rbase + reg;
#pragma unroll
        for (int nt = 0; nt < 8; ++nt) {
          float vv = acc[nt][reg] + bs[nt];
          if constexpr (MODE == 0) outF[(size_t)row * outw + co + nt * 16 + cl] = vv;
          else outB[(size_t)row * outw + co + nt * 16 + cl] = f2bf(vv);
        }
      }
    }
  }
}

// standalone GEMM kernel (updln / pq layer1 / out)
template <int KS, bool AF32, bool DUAL, int MODE>
__global__ __launch_bounds__(256, DUAL ? 1 : 2) void gemm3(
    const void* __restrict__ A0v, const unsigned short* __restrict__ A1,
    const unsigned short* __restrict__ W, const float* __restrict__ bias,
    const int* __restrict__ deg, const float* __restrict__ bias2,
    const float* __restrict__ gamma, const float* __restrict__ beta,
    const unsigned short* __restrict__ hres, float* __restrict__ outF,
    unsigned short* __restrict__ outB, int outw) {
  __shared__ short Bs[KS * 8 * 512];
  gemm3_dev<KS, AF32, DUAL, MODE>(Bs, blockIdx.x, gridDim.x, blockIdx.y, A0v, A1, W, bias,
                                  deg, bias2, gamma, beta, hres, outF, outB, outw);
}

// ================= merged kernels: CSR stages hidden under GEMM =================
union MergedSmem1 { BscatSmem b; short Bs[32 * 512]; };
__global__ __launch_bounds__(256, 2) void k_bscat_enc(
    const int* __restrict__ ei, int* __restrict__ bcursor, unsigned int* __restrict__ ebuf,
    const float* __restrict__ x, const unsigned short* __restrict__ Wenc,
    const float* __restrict__ b_enc, unsigned short* __restrict__ hb) {
  __shared__ MergedSmem1 sm;
  if (blockIdx.x < NSLICE) {
    bscatter_dev(sm.b, ei, bcursor, ebuf, blockIdx.x);
  } else {
    gemm3_dev<4, true, false, 1>(sm.Bs, blockIdx.x - NSLICE, 512, 0, x, nullptr, Wenc, b_enc,
                                 nullptr, nullptr, nullptr, nullptr, nullptr, nullptr, hb, HID);
  }
}

union MergedSmem2 { Sort64Smem s; short Bs[32 * 512]; };
__global__ __launch_bounds__(256, 2) void k_sort_pq(
    const unsigned int* __restrict__ ebuf, const int* __restrict__ boff,
    unsigned short* __restrict__ esrc, int* __restrict__ noff, int* __restrict__ counts,
    const unsigned short* __restrict__ hb, const unsigned short* __restrict__ Wpq,
    unsigned short* __restrict__ pq) {
  __shared__ MergedSmem2 sm;
  if (blockIdx.x < NBKT) {
    sort64_dev(sm.s, ebuf, boff, esrc, noff, counts, blockIdx.x);
  } else {
    int bb = blockIdx.x - NBKT;
    gemm3_dev<4, false, false, 1>(sm.Bs, bb & 511, 512, bb >> 9, hb, nullptr, Wpq, nullptr,
                                  nullptr, nullptr, nullptr, nullptr, nullptr, nullptr, pq, 256);
  }
}

// ================= aggregation: wave per node, uint4 gathers (16 lanes/row), 16 edges/iter ==
__device__ __forceinline__ void acc8(float* acc, const float* qf, uint4 u) {
  acc[0] += fmaxf(bflo(u.x) + qf[0], 0.f);
  acc[1] += fmaxf(bfhi(u.x) + qf[1], 0.f);
  acc[2] += fmaxf(bflo(u.y) + qf[2], 0.f);
  acc[3] += fmaxf(bfhi(u.y) + qf[3], 0.f);
  acc[4] += fmaxf(bflo(u.z) + qf[4], 0.f);
  acc[5] += fmaxf(bfhi(u.z) + qf[5], 0.f);
  acc[6] += fmaxf(bflo(u.w) + qf[6], 0.f);
  acc[7] += fmaxf(bfhi(u.w) + qf[7], 0.f);
}

__global__ __launch_bounds__(256) void aggregate5_kernel(
    const uint4* __restrict__ pq4, const float* __restrict__ bm1,
    const int* __restrict__ noff, const unsigned short* __restrict__ esrc,
    uint4* __restrict__ rb4) {
  const int node = blockIdx.x * 4 + (threadIdx.x >> 6);
  const int lane = threadIdx.x & 63;
  const int l = lane & 15;   // uint4 slot: channels 8l..8l+7
  const int eh = lane >> 4;  // edge slot within group of 4
  uint4 qv = pq4[(size_t)node * 32 + 16 + l];  // q-half
  float4 b0 = *(const float4*)(bm1 + 8 * l);
  float4 b1 = *(const float4*)(bm1 + 8 * l + 4);
  float qf[8] = {bflo(qv.x) + b0.x, bfhi(qv.x) + b0.y, bflo(qv.y) + b0.z, bfhi(qv.y) + b0.w,
                 bflo(qv.z) + b1.x, bfhi(qv.z) + b1.y, bflo(qv.w) + b1.z, bfhi(qv.w) + b1.w};
  float acc[8] = {0.f, 0.f, 0.f, 0.f, 0.f, 0.f, 0.f, 0.f};
  const int i0 = noff[node], i1 = noff[node + 1];
  const int nfull = (i1 - i0) >> 4;  // 16 edges per full wave-iter
  int idx = i0 + eh;
  for (int j = 0; j < nfull; ++j, idx += 16) {
    int s0 = esrc[idx], s1 = esrc[idx + 4], s2 = esrc[idx + 8], s3 = esrc[idx + 12];
    uint4 u0 = pq4[(size_t)s0 * 32 + l];
    uint4 u1 = pq4[(size_t)s1 * 32 + l];
    uint4 u2 = pq4[(size_t)s2 * 32 + l];
    uint4 u3 = pq4[(size_t)s3 * 32 + l];
    acc8(acc, qf, u0);
    acc8(acc, qf, u1);
    acc8(acc, qf, u2);
    acc8(acc, qf, u3);
  }
  while (idx < i1) {  // tail: <16 edges, 4 at a time, exec-masked
    uint4 u = pq4[(size_t)esrc[idx] * 32 + l];
    acc8(acc, qf, u);
    idx += 4;
  }
#pragma unroll
  for (int j = 0; j < 8; ++j) {
    acc[j] += __shfl_xor(acc[j], 16);
    acc[j] += __shfl_xor(acc[j], 32);
  }
  if (lane < 16) {
    uint4 r;
    r.x = pack2(acc[0], acc[1]);
    r.y = pack2(acc[2], acc[3]);
    r.z = pack2(acc[4], acc[5]);
    r.w = pack2(acc[6], acc[7]);
    rb4[(size_t)node * 16 + l] = r;
  }
}

extern "C" void kernel_launch(void* const* d_in, const int* in_sizes, int n_in,
                              void* d_out, int out_size, void* d_ws, size_t ws_size,
                              hipStream_t stream) {
  const float* x     = (const float*)d_in[0];
  const int*   ei    = (const int*)d_in[1];
  const float* W_enc = (const float*)d_in[2];
  const float* b_enc = (const float*)d_in[3];
  const float* Wm1   = (const float*)d_in[4];
  const float* bm1   = (const float*)d_in[5];
  const float* Wm2   = (const float*)d_in[6];
  const float* bm2   = (const float*)d_in[7];
  const float* Wu    = (const float*)d_in[8];
  const float* bu    = (const float*)d_in[9];
  const float* gamma = (const float*)d_in[10];
  const float* beta  = (const float*)d_in[11];
  const float* W_out = (const float*)d_in[12];
  const float* b_out = (const float*)d_in[13];
  float* out = (float*)d_out;

  char* ws = (char*)d_ws;
  const size_t NBH = (size_t)N_NODES * HID * 2;  // 12.8 MB

  unsigned short* hb = (unsigned short*)(ws);            // [N][128] bf16
  unsigned short* pq = (unsigned short*)(ws + NBH);      // [N][256] bf16
  unsigned short* rb = (unsigned short*)(ws + 3 * NBH);  // [N][128] bf16
  char* wp = ws + 4 * NBH;
  unsigned short* Wenc_b = (unsigned short*)wp;          // 16384
  unsigned short* Wout_b = Wenc_b + 16384;               // 16384
  unsigned short* Wpq_b  = Wout_b + 16384;               // 2*32768
  unsigned short* Wcat_b = Wpq_b + 65536;                // 2*32768
  float*          bfold  = (float*)(Wcat_b + 65536);     // 256
  int* counts  = (int*)(bfold + 256);                    // [N] deg
  int* noff    = counts + N_NODES;                       // [N+1] exact CSR offsets
  int* boff    = noff + N_NODES + 1;                     // NBKT+1
  int* bcounts = boff + NBKT + 1;                        // NBKT
  int* bcursor = bcounts + NBKT;                         // NBKT
  unsigned short* esrc = (unsigned short*)(bcursor + NBKT);  // [E] u16 src by exact dst
  unsigned int* ebuf = (unsigned int*)(esrc + N_EDGES);      // [E] bucket-grouped
  int* shist = (int*)(ebuf + N_EDGES);                       // [NSLICE][NBKT]

  // 1. weight prep || per-slice bucket histograms (no atomics on globals, no memset)
  prep_hist_kernel<<<449 + NSLICE, 256, 0, stream>>>(
      W_enc, W_out, Wm1, Wu, Wm2, bm2, (unsigned int*)Wenc_b, (unsigned int*)Wout_b,
      (unsigned int*)Wpq_b, Wcat_b, bfold, ei, shist);
  // 2-3. column-sum -> exclusive scan
  colsum_kernel<<<4, 256, 0, stream>>>(shist, bcounts);
  bscan_kernel<<<1, 1024, 0, stream>>>(bcounts, boff, bcursor);
  // 4. bucket scatter || enc GEMM (h = x @ W_enc.T + b_enc -> bf16 hb)
  k_bscat_enc<<<NSLICE + 512, 256, 0, stream>>>(ei, bcursor, ebuf, x, Wenc_b, b_enc, hb);
  // 5. sort64 (exact CSR) || pq GEMM layer 0
  k_sort_pq<<<NBKT + 1024, 256, 0, stream>>>(ebuf, boff, esrc, noff, counts, hb, Wpq_b, pq);

  for (int l = 0; l < 2; ++l) {
    const unsigned short* Wcatl = Wcat_b + l * 32768;
    const float* bm1l = bm1 + l * HID;
    const float* bul  = bu + l * HID;
    const float* bfl  = bfold + l * HID;
    const float* gl   = gamma + l * HID;
    const float* bl   = beta + l * HID;

    // r = segsum(relu(p[src]+q[dst]+bm1)) over exact per-node runs
    aggregate5_kernel<<<12500, 256, 0, stream>>>((const uint4*)pq, bm1l, noff, esrc,
                                                 (uint4*)rb);
    // h = LN(h + h@Wua.T + r@Wfold.T + deg*bfold + bu)*gamma+beta (in-place)
    gemm3<8, false, true, 2><<<256, 256, 0, stream>>>(
        hb, rb, Wcatl, bul, counts, bfl, gl, bl, hb, nullptr, hb, HID);
    // pq for layer 1
    if (l == 0)
      gemm3<4, false, false, 1><<<dim3(512, 2), 256, 0, stream>>>(
          hb, nullptr, Wpq_b + 32768, nullptr, nullptr, nullptr, nullptr, nullptr, nullptr,
          nullptr, pq, 256);
  }

  // out = h @ W_out.T + b_out (f32)
  gemm3<4, false, false, 0><<<512, 256, 0, stream>>>(
      hb, nullptr, Wout_b, b_out, nullptr, nullptr, nullptr, nullptr, nullptr,
      out, nullptr, HID);
}